// Round 1
// 2087.369 us; speedup vs baseline: 2.0451x; 2.0451x over previous
//
#include <hip/hip_runtime.h>
#include <math.h>

// Problem constants (match reference)
constexpr int Bq  = 256;
constexpr int S1q = 512;
constexpr int S2q = 64;
constexpr int Hq  = 768;
constexpr int OPCq = 64;
constexpr int OTq  = 128;   // OPC + S2
#define NEGq (-1e12f)

typedef unsigned int   u32;
typedef unsigned short u16;

// Output layout (flat f32 concat):
//  num_score [256,128]      @ 0        (32768)
//  node      [256,1,768]    @ 32768    (196608)
//  context   [256,1,768]    @ 229376   (196608)
//  emb_all   [256,128,768]  @ 425984   (25165824)

__device__ __forceinline__ float fast_tanh(float x) {
    x = fminf(fmaxf(x, -15.f), 15.f);
    float e = __expf(2.f * x);
    return (e - 1.f) / (e + 1.f);
}
__device__ __forceinline__ float fast_sigmoid(float x) {
    x = fminf(fmaxf(x, -30.f), 30.f);
    return 1.f / (1.f + __expf(-x));
}

// fp32 -> bf16 round-to-nearest-even (bit trick; inputs are finite, moderate range)
__device__ __forceinline__ u16 bf16_rne(float x) {
    union { float f; u32 u; } c; c.f = x;
    return (u16)((c.u + 0x7fffu + ((c.u >> 16) & 1u)) >> 16);
}
__device__ __forceinline__ float bf16_f(u16 h) {
    union { u32 u; float f; } c; c.u = ((u32)h) << 16; return c.f;
}

typedef __attribute__((ext_vector_type(8))) short bf16x8_t;   // 8 bf16 = 4 VGPRs (MFMA A/B frag)
typedef __attribute__((ext_vector_type(4))) float f32x4_t;    // MFMA C/D frag
#define MFMA16 __builtin_amdgcn_mfma_f32_16x16x32_bf16

// ---------------------------------------------------------------------------
// K1: node[b,h] (unchanged)
// ---------------------------------------------------------------------------
template <int BT>
__global__ __launch_bounds__(256)
void node_kernel(const float* __restrict__ cur_emb, const float* __restrict__ left_emb,
                 const float* __restrict__ W_l,  const float* __restrict__ b_l,
                 const float* __restrict__ W_lg, const float* __restrict__ b_lg,
                 const float* __restrict__ W_r,  const float* __restrict__ b_r,
                 const float* __restrict__ W_rg, const float* __restrict__ b_rg,
                 const int* __restrict__ has_left, float* __restrict__ node_out) {
    __shared__ float lcs[BT][2 * Hq];   // [left | current]
    const int tid = threadIdx.x;
    const int h  = blockIdx.x * 256 + tid;
    const int b0 = blockIdx.y * BT;
    for (int idx = tid; idx < BT * Hq; idx += 256) {
        int j = idx / Hq, k = idx % Hq;
        lcs[j][k]      = left_emb[(b0 + j) * Hq + k];
        lcs[j][Hq + k] = cur_emb[(b0 + j) * Hq + k];
    }
    __syncthreads();
    float agl[BT], atl[BT], agr[BT], atr[BT];
#pragma unroll
    for (int j = 0; j < BT; j++) { agl[j] = b_l[h]; atl[j] = b_lg[h]; agr[j] = b_r[h]; atr[j] = b_rg[h]; }
    for (int k = 0; k < Hq; k++) {
        float wl = W_l[k * Hq + h], wlg = W_lg[k * Hq + h];
#pragma unroll
        for (int j = 0; j < BT; j++) { float x = lcs[j][Hq + k]; agl[j] += x * wl; atl[j] += x * wlg; }
    }
    for (int k = 0; k < 2 * Hq; k++) {
        float wr = W_r[k * Hq + h], wrg = W_rg[k * Hq + h];
#pragma unroll
        for (int j = 0; j < BT; j++) { float x = lcs[j][k]; agr[j] += x * wr; atr[j] += x * wrg; }
    }
#pragma unroll
    for (int j = 0; j < BT; j++) {
        int b = b0 + j;
        float n = has_left[b] ? fast_tanh(agr[j]) * fast_sigmoid(atr[j])
                              : fast_tanh(agl[j]) * fast_sigmoid(atl[j]);
        node_out[b * Hq + h] = n;
    }
}

// ---------------------------------------------------------------------------
// K2 (generic): out[m,h] = bias[h] + A1@W[0:K1] + A2@W[K1:K1+K2]  (unchanged)
// ---------------------------------------------------------------------------
template <int BT>
__global__ __launch_bounds__(256)
void proj_kernel(const float* __restrict__ A1, const float* __restrict__ A2,
                 int K1, int K2,
                 const float* __restrict__ W, const float* __restrict__ bias,
                 float* __restrict__ out) {
    __shared__ float As[BT][2 * Hq];
    const int tid = threadIdx.x;
    const int h  = blockIdx.x * 256 + tid;
    const int b0 = blockIdx.y * BT;
    const int K = K1 + K2;
    for (int idx = tid; idx < BT * K1; idx += 256) {
        int j = idx / K1, k = idx % K1;
        As[j][k] = A1[(b0 + j) * K1 + k];
    }
    if (A2) {
        for (int idx = tid; idx < BT * K2; idx += 256) {
            int j = idx / K2, k = idx % K2;
            As[j][K1 + k] = A2[(b0 + j) * K2 + k];
        }
    }
    __syncthreads();
    float acc[BT];
#pragma unroll
    for (int j = 0; j < BT; j++) acc[j] = bias ? bias[h] : 0.f;
    for (int k = 0; k < K; k++) {
        float w = W[k * Hq + h];
#pragma unroll
        for (int j = 0; j < BT; j++) acc[j] += As[j][k] * w;
    }
#pragma unroll
    for (int j = 0; j < BT; j++) out[(b0 + j) * Hq + h] = acc[j];
}

// ---------------------------------------------------------------------------
// K-prep: W [768 k][768 n] fp32  ->  frag-major bf16 hi/lo for MFMA B-operand.
// Chunk for (col16 = n>>4, kt = k>>5, lane = (kgrp<<4)|(n&15)) holds
// bf16 of W[kt*32 + kgrp*8 + e][col16*16 + (n&15)], e = 0..7  (one uint4).
// A wave's B-frag load becomes ONE fully-coalesced 1024B global_load_dwordx4.
// Grid (12,12), 64x64 tiles via padded-LDS transpose.
// ---------------------------------------------------------------------------
__global__ __launch_bounds__(256)
void w_prep_kernel(const float* __restrict__ W,
                   uint4* __restrict__ Wf_hi, uint4* __restrict__ Wf_lo) {
    __shared__ float tile[64][65];
    const int tid = threadIdx.x;
    const int k0 = blockIdx.x * 64, n0 = blockIdx.y * 64;
    const int tx = tid & 63, tyy = tid >> 6;
    for (int u = tyy; u < 64; u += 4)
        tile[u][tx] = W[(size_t)(k0 + u) * Hq + n0 + tx];
    __syncthreads();
    const int l15 = tid & 15, lg = (tid >> 4) & 3, ktl = (tid >> 6) & 1;
    for (int c16 = tid >> 7; c16 < 4; c16 += 2) {
        const int kl = ktl * 32 + lg * 8;
        const int nl = c16 * 16 + l15;
        u32 h[4], l[4];
#pragma unroll
        for (int p = 0; p < 4; p++) {
            float a = tile[kl + 2 * p][nl], b = tile[kl + 2 * p + 1][nl];
            u16 ha = bf16_rne(a), hb = bf16_rne(b);
            u16 la = bf16_rne(a - bf16_f(ha)), lb = bf16_rne(b - bf16_f(hb));
            h[p] = (u32)ha | ((u32)hb << 16);
            l[p] = (u32)la | ((u32)lb << 16);
        }
        size_t idx = ((size_t)((n0 >> 4) + c16) * 24 + (k0 >> 5) + ktl) * 64 + lg * 16 + l15;
        Wf_hi[idx] = make_uint4(h[0], h[1], h[2], h[3]);
        Wf_lo[idx] = make_uint4(l[0], l[1], l[2], l[3]);
    }
}

// ---------------------------------------------------------------------------
// K3 (MFMA, bf16x3): out[row] = sum_h v[h] * tanh( (A[row,:]@W)[h] + addv[b,h] )
// A, W split hi+lo bf16; acc = Ah*Wh + Al*Wh + Ah*Wl (fp32 MFMA accum) ->
// ~17-bit effective mantissa, error ~1e-5 (below existing fast_tanh absmax).
// Block: 512 thr = 8 waves (wr 0..1 x wc 0..3). Tile 128 rows x 256 cols,
// 3 column passes. BK=32, A reg-prefetched then cvt'd into LDS [row][k]
// (64B row stride -> bank-uniform ds_read_b128 frags). W frags straight from
// L2 via the frag-major layout above. 16x16x32 MFMA; C/D layout per m89:
// col = lane&15, row = (lane>>4)*4 + reg.
// ---------------------------------------------------------------------------
__global__ __launch_bounds__(512)
void fused_tanh_dot_mfma(const float* __restrict__ A,      // [M][768] fp32
                         const uint4* __restrict__ Wf_hi,  // frag-major bf16
                         const uint4* __restrict__ Wf_lo,
                         const float* __restrict__ addv,   // [nb][768]
                         const float* __restrict__ vvec,   // [768]
                         float* __restrict__ out,
                         const int* __restrict__ maskp,    // nullable
                         int shift, int ostride, int ooff) {
    __shared__ __align__(16) u16 Ah[128 * 32];
    __shared__ __align__(16) u16 Al[128 * 32];
    __shared__ float part[4][128];     // per-wc row partials (race-free slots)
    const int tid  = threadIdx.x;
    const int lane = tid & 63;
    const int wid  = tid >> 6, wr = wid >> 2, wc = wid & 3;
    const int l15  = lane & 15, lg = lane >> 4;
    const int rowbase = blockIdx.x * 128;

    part[tid >> 7][tid & 127] = 0.f;

    // staging map: thread -> (row, 8-wide k chunk)
    const int srow = tid >> 2, sk = (tid & 3) * 8;
    const float* Arow = A + (size_t)(rowbase + srow) * Hq + sk;

    // epilogue batch index is uniform per wave (128 | 512 for step4; 64-row
    // wave granularity for step8's shift=6)
    const int bw = (rowbase + wr * 64) >> shift;
    const float* ad = addv + (size_t)bw * Hq;
    const int arow0 = wr * 64 + l15;

    for (int ct = 0; ct < 3; ct++) {
        f32x4_t acc[4][4];
#pragma unroll
        for (int i = 0; i < 4; i++)
#pragma unroll
            for (int j = 0; j < 4; j++) acc[i][j] = (f32x4_t){0.f, 0.f, 0.f, 0.f};

        const int c0 = ct * 16 + wc * 4;   // global col16 base for this wave
        float4 f0 = *(const float4*)(Arow);
        float4 f1 = *(const float4*)(Arow + 4);
        for (int kt = 0; kt < 24; kt++) {
            // prefetch next A chunk (lands under this kt's MFMAs)
            float4 n0 = f0, n1 = f1;
            if (kt < 23) {
                n0 = *(const float4*)(Arow + (kt + 1) * 32);
                n1 = *(const float4*)(Arow + (kt + 1) * 32 + 4);
            }
            __syncthreads();   // previous compute done reading LDS
            {
                float xs[8] = {f0.x, f0.y, f0.z, f0.w, f1.x, f1.y, f1.z, f1.w};
                u32 h[4], l[4];
#pragma unroll
                for (int p = 0; p < 4; p++) {
                    u16 ha = bf16_rne(xs[2 * p]), hb = bf16_rne(xs[2 * p + 1]);
                    u16 la = bf16_rne(xs[2 * p] - bf16_f(ha));
                    u16 lb = bf16_rne(xs[2 * p + 1] - bf16_f(hb));
                    h[p] = (u32)ha | ((u32)hb << 16);
                    l[p] = (u32)la | ((u32)lb << 16);
                }
                *(uint4*)&Ah[srow * 32 + sk] = make_uint4(h[0], h[1], h[2], h[3]);
                *(uint4*)&Al[srow * 32 + sk] = make_uint4(l[0], l[1], l[2], l[3]);
            }
            __syncthreads();

            bf16x8_t ahf[4], alf[4];
#pragma unroll
            for (int i = 0; i < 4; i++) {
                ahf[i] = *(const bf16x8_t*)&Ah[(arow0 + i * 16) * 32 + lg * 8];
                alf[i] = *(const bf16x8_t*)&Al[(arow0 + i * 16) * 32 + lg * 8];
            }
#pragma unroll
            for (int j = 0; j < 4; j++) {
                uint4 wh4 = Wf_hi[((size_t)(c0 + j) * 24 + kt) * 64 + lane];
                uint4 wl4 = Wf_lo[((size_t)(c0 + j) * 24 + kt) * 64 + lane];
                bf16x8_t wh = *(bf16x8_t*)&wh4;
                bf16x8_t wl = *(bf16x8_t*)&wl4;
#pragma unroll
                for (int i = 0; i < 4; i++) {
                    acc[i][j] = MFMA16(ahf[i], wh, acc[i][j], 0, 0, 0);
                    acc[i][j] = MFMA16(alf[i], wh, acc[i][j], 0, 0, 0);
                    acc[i][j] = MFMA16(ahf[i], wl, acc[i][j], 0, 0, 0);
                }
            }
            f0 = n0; f1 = n1;
        }

        // epilogue for this 256-col pass: tanh + dot(v), reduce over 16 col-lanes
        float sacc[4][4];
#pragma unroll
        for (int i = 0; i < 4; i++)
#pragma unroll
            for (int r = 0; r < 4; r++) sacc[i][r] = 0.f;
#pragma unroll
        for (int j = 0; j < 4; j++) {
            const int col = ct * 256 + wc * 64 + j * 16 + l15;
            const float vv = vvec[col];
            const float av = ad[col];
#pragma unroll
            for (int i = 0; i < 4; i++)
#pragma unroll
                for (int r = 0; r < 4; r++)
                    sacc[i][r] += vv * fast_tanh(acc[i][j][r] + av);
        }
#pragma unroll
        for (int i = 0; i < 4; i++)
#pragma unroll
            for (int r = 0; r < 4; r++) {
                float s = sacc[i][r];
                s += __shfl_xor(s, 1);
                s += __shfl_xor(s, 2);
                s += __shfl_xor(s, 4);
                s += __shfl_xor(s, 8);
                if (l15 == 0) {
                    // slot (wc, row) touched by exactly one lane -> no race
                    part[wc][wr * 64 + i * 16 + lg * 4 + r] += s;
                }
            }
    }
    __syncthreads();
    if (tid < 128) {
        int grow = rowbase + tid;
        int b = grow >> shift;
        int j = grow - (b << shift);
        int oidx = b * ostride + ooff + j;
        float val = part[0][tid] + part[1][tid] + part[2][tid] + part[3][tid];
        if (maskp && maskp[oidx]) val = NEGq;
        out[oidx] = val;
    }
}

// ---------------------------------------------------------------------------
// K4: masked softmax over S1 per b, in place (unchanged)
// ---------------------------------------------------------------------------
__global__ __launch_bounds__(256)
void softmax_kernel(float* __restrict__ e, const int* __restrict__ smask) {
    __shared__ float red[256];
    const int b = blockIdx.x, tid = threadIdx.x;
    float e0 = e[b * S1q + tid], e1 = e[b * S1q + 256 + tid];
    if (smask[b * S1q + tid]) e0 = NEGq;
    if (smask[b * S1q + 256 + tid]) e1 = NEGq;
    red[tid] = fmaxf(e0, e1);
    __syncthreads();
    for (int off = 128; off > 0; off >>= 1) {
        if (tid < off) red[tid] = fmaxf(red[tid], red[tid + off]);
        __syncthreads();
    }
    float mx = red[0];
    __syncthreads();
    float p0 = __expf(e0 - mx), p1 = __expf(e1 - mx);
    red[tid] = p0 + p1;
    __syncthreads();
    for (int off = 128; off > 0; off >>= 1) {
        if (tid < off) red[tid] += red[tid + off];
        __syncthreads();
    }
    float inv = 1.f / red[0];
    e[b * S1q + tid] = p0 * inv;
    e[b * S1q + 256 + tid] = p1 * inv;
}

// ---------------------------------------------------------------------------
// K5: context[b,h] = sum_s attn[b,s] * enc[b,s,h]  (unchanged)
// ---------------------------------------------------------------------------
__global__ __launch_bounds__(256)
void context_kernel(const float* __restrict__ attn, const float* __restrict__ enc,
                    float* __restrict__ ctx_out) {
    __shared__ float attn_s[S1q];
    const int tid = threadIdx.x;
    const int b = blockIdx.y;
    const int h = blockIdx.x * 256 + tid;
    attn_s[tid]       = attn[b * S1q + tid];
    attn_s[256 + tid] = attn[b * S1q + 256 + tid];
    __syncthreads();
    float c = 0.f;
    const float* ep = enc + (size_t)b * S1q * Hq + h;
    for (int s = 0; s < S1q; s++) c += attn_s[s] * ep[(size_t)s * Hq];
    ctx_out[b * Hq + h] = c;
}

// ---------------------------------------------------------------------------
// K6: op/const scores (unchanged)
// ---------------------------------------------------------------------------
__global__ __launch_bounds__(256)
void opscore_kernel(const float* __restrict__ scorebase, const float* __restrict__ opproj,
                    const float* __restrict__ vsc, const int* __restrict__ cmask,
                    float* __restrict__ num_score) {
    __shared__ float sb[Hq];
    __shared__ float red[256];
    const int b = blockIdx.x, tid = threadIdx.x;
    for (int i = tid; i < Hq; i += 256) sb[i] = scorebase[b * Hq + i];
    __syncthreads();
    const int o = tid & 63, q = tid >> 6;
    float partl = 0.f;
    for (int h = q * 192; h < (q + 1) * 192; h++)
        partl += vsc[h] * fast_tanh(sb[h] + opproj[o * Hq + h]);
    red[tid] = partl;
    __syncthreads();
    if (tid < 64) {
        float val = red[tid] + red[tid + 64] + red[tid + 128] + red[tid + 192];
        int oidx = b * OTq + tid;
        num_score[oidx] = cmask[oidx] ? NEGq : val;
    }
}

// ---------------------------------------------------------------------------
// K7: emb_all = concat(broadcast(emb_op_const), var_pades) (unchanged)
// NOTE: runs LAST — its output region doubles as scratch for Wf_* earlier.
// ---------------------------------------------------------------------------
__global__ __launch_bounds__(256)
void emb_all_kernel(const float* __restrict__ opc, const float* __restrict__ var,
                    float4* __restrict__ out) {
    const long long total = (long long)Bq * OTq * (Hq / 4);
    for (long long idx = (long long)blockIdx.x * 256 + threadIdx.x; idx < total;
         idx += (long long)gridDim.x * 256) {
        long long b = idx / (OTq * (Hq / 4));
        int rem = (int)(idx - b * (OTq * (Hq / 4)));
        int o = rem / (Hq / 4), hv = rem % (Hq / 4);
        float4 val;
        if (o < OPCq) val = *(const float4*)&opc[o * Hq + hv * 4];
        else          val = *(const float4*)&var[((b * S2q) + (o - OPCq)) * (long long)Hq + hv * 4];
        out[idx] = val;
    }
}

extern "C" void kernel_launch(void* const* d_in, const int* in_sizes, int n_in,
                              void* d_out, int out_size, void* d_ws, size_t ws_size,
                              hipStream_t stream) {
    const float* cur     = (const float*)d_in[0];
    const float* left    = (const float*)d_in[1];
    const float* enc     = (const float*)d_in[2];
    const float* var     = (const float*)d_in[3];
    const float* opc     = (const float*)d_in[4];
    const float* W_l     = (const float*)d_in[5];
    const float* b_l     = (const float*)d_in[6];
    const float* W_lg    = (const float*)d_in[7];
    const float* b_lg    = (const float*)d_in[8];
    const float* W_r     = (const float*)d_in[9];
    const float* b_r     = (const float*)d_in[10];
    const float* W_rg    = (const float*)d_in[11];
    const float* b_rg    = (const float*)d_in[12];
    const float* W_attn  = (const float*)d_in[13];
    const float* b_attn  = (const float*)d_in[14];
    const float* v_attn  = (const float*)d_in[15];
    const float* W_score = (const float*)d_in[16];
    const float* b_score = (const float*)d_in[17];
    const float* v_score = (const float*)d_in[18];
    const int*   has_left= (const int*)d_in[19];
    const int*   smask   = (const int*)d_in[20];
    const int*   cmask   = (const int*)d_in[21];

    float* out       = (float*)d_out;
    float* num_score = out;            // [256,128]
    float* node      = out + 32768;    // [256,768]
    float* context   = out + 229376;   // [256,768]
    float* emb_all   = out + 425984;   // [256,128,768]

    float* ws        = (float*)d_ws;
    float* nodeproj  = ws;                       // 196608 f32
    float* energy    = ws + 196608;              // 131072 f32 (becomes attn in place)
    float* scorebase = ws + 196608 + 131072;     // 196608 f32
    float* opproj    = scorebase + 196608;       // 49152 f32

    // Scratch for frag-major bf16 weights lives at the START of the emb_all
    // output region (4.7 MB of 100 MB); emb_all_kernel overwrites it last.
    uint4* Wf_attn_hi = (uint4*)emb_all;
    uint4* Wf_attn_lo = Wf_attn_hi + 73728;     // 48*24*64 uint4 = 1.125 MB each
    uint4* Wf_sc_hi   = Wf_attn_lo + 73728;
    uint4* Wf_sc_lo   = Wf_sc_hi + 73728;

    // 0. weight prep (independent of everything else)
    w_prep_kernel<<<dim3(12, 12), 256, 0, stream>>>(W_attn + (size_t)768 * Hq,
                                                    Wf_attn_hi, Wf_attn_lo);
    w_prep_kernel<<<dim3(12, 12), 256, 0, stream>>>(W_score + (size_t)1536 * Hq,
                                                    Wf_sc_hi, Wf_sc_lo);
    // 1. node
    node_kernel<8><<<dim3(3, 32), 256, 0, stream>>>(cur, left, W_l, b_l, W_lg, b_lg,
                                                    W_r, b_r, W_rg, b_rg, has_left, node);
    // 2. nodeproj = node @ W_attn[:768] + b_attn
    proj_kernel<8><<<dim3(3, 32), 256, 0, stream>>>(node, nullptr, 768, 0, W_attn, b_attn, nodeproj);
    // 3. opproj = emb_op_const @ W_score[1536:2304]   (batch-independent)
    proj_kernel<8><<<dim3(3, 8), 256, 0, stream>>>(opc, nullptr, 768, 0,
                                                   W_score + (size_t)1536 * Hq, nullptr, opproj);
    // 4. energy[b,s] = v_attn . tanh(nodeproj[b] + enc[b,s]@W_attn[768:1536])  [MFMA bf16x3]
    fused_tanh_dot_mfma<<<1024, 512, 0, stream>>>(enc, Wf_attn_hi, Wf_attn_lo, nodeproj,
                                                  v_attn, energy, nullptr, 9, S1q, 0);
    // 5. masked softmax (in place -> attn)
    softmax_kernel<<<256, 256, 0, stream>>>(energy, smask);
    // 6. context
    context_kernel<<<dim3(3, 256), 256, 0, stream>>>(energy, enc, context);
    // 7. scorebase = [node, context] @ W_score[:1536] + b_score
    proj_kernel<8><<<dim3(3, 32), 256, 0, stream>>>(node, context, 768, 768, W_score, b_score, scorebase);
    // 8. var scores -> num_score[:, 64:128] with candi_mask  [MFMA bf16x3]
    fused_tanh_dot_mfma<<<128, 512, 0, stream>>>(var, Wf_sc_hi, Wf_sc_lo, scorebase,
                                                 v_score, num_score, cmask, 6, OTq, OPCq);
    // 9. op/const scores -> num_score[:, 0:64] with candi_mask
    opscore_kernel<<<256, 256, 0, stream>>>(scorebase, opproj, v_score, cmask, num_score);
    // 10. emb_all copy-out (overwrites the Wf_* scratch)
    emb_all_kernel<<<4096, 256, 0, stream>>>(opc, var, (float4*)emb_all);
}